// Round 1
// baseline (101.313 us; speedup 1.0000x reference)
//
#include <hip/hip_runtime.h>
#include <stdint.h>

#define H_HEADS 16
#define ADIM    128
#define SLEN    2048
#define DMODEL  2048

typedef __attribute__((ext_vector_type(8))) short  short8;   // bf16x8 MFMA frag (4 VGPRs)
typedef __attribute__((ext_vector_type(4))) float  float4v;  // fp32x4 MFMA acc
typedef __attribute__((ext_vector_type(4))) unsigned short ushort4v;

typedef const __attribute__((address_space(1))) unsigned int gas_u32;
typedef __attribute__((address_space(3))) unsigned int las_u32;

union F4 { float4 v; float a[4]; };

__device__ __forceinline__ unsigned short f2bf(float f) {
  union { float f; unsigned u; } v; v.f = f;
  unsigned r = v.u + 0x7FFFu + ((v.u >> 16) & 1u);   // RNE
  return (unsigned short)(r >> 16);
}

// log2(10000)/64
#define ROPE_C 0.20762050593045935f

// ---------------- prep_k: RoPE(K) -> bf16, layout [B*H][S][128],
// 16B-chunk XOR swizzle within each 128-elem row: chunk ^= (s & 7).
__global__ __launch_bounds__(256) void prep_k(const float* __restrict__ xk,
                                              unsigned short* __restrict__ kw) {
  int t = blockIdx.x * 256 + threadIdx.x;       // B * 2^19 threads total
  int i4 = t & 15;
  int h  = (t >> 4) & (H_HEADS - 1);
  int s  = (t >> 8) & (SLEN - 1);
  int b  = t >> 19;
  int i0 = i4 * 4;
  long ib = ((long)(b * SLEN + s)) * DMODEL + h * ADIM;
  F4 x1, x2;
  x1.v = *(const float4*)(xk + ib + i0);
  x2.v = *(const float4*)(xk + ib + i0 + 64);
  ushort4v o1, o2;
  #pragma unroll
  for (int j = 0; j < 4; ++j) {
    float inv = exp2f(-(float)(i0 + j) * ROPE_C);
    float ang = (float)s * inv;
    float sn, cs;
    sincosf(ang, &sn, &cs);
    o1[j] = f2bf( x1.a[j] * cs + x2.a[j] * sn);
    o2[j] = f2bf(-x1.a[j] * sn + x2.a[j] * cs);
  }
  long row = ((long)((b * H_HEADS + h) * SLEN + s)) * ADIM;
  int swz = s & 7;
  int c1 = ((((i0     ) >> 3) ^ swz) << 3) | (i0 & 7);
  int c2 = ((((i0 + 64) >> 3) ^ swz) << 3) | (i0 & 7);
  *(ushort4v*)(kw + row + c1) = o1;
  *(ushort4v*)(kw + row + c2) = o2;
}

// ---------------- prep_v: transpose V per 64-key tile -> bf16
// layout [B*H][tile][d=128][key=64], 16B-chunk XOR swizzle: chunk ^= (d & 7).
__global__ __launch_bounds__(256) void prep_v(const float* __restrict__ xv,
                                              unsigned short* __restrict__ vw) {
  __shared__ float lv[64 * 129];
  int jt = blockIdx.x;            // key tile 0..31
  int bh = blockIdx.y;
  int b = bh >> 4, h = bh & (H_HEADS - 1);
  int t = threadIdx.x;
  #pragma unroll
  for (int it = 0; it < 8; ++it) {            // 2048 float4 reads
    int id  = it * 256 + t;
    int row = id >> 5;
    int c4  = (id & 31) * 4;
    F4 x;
    x.v = *(const float4*)(xv + ((long)(b * SLEN + jt * 64 + row)) * DMODEL + h * ADIM + c4);
    #pragma unroll
    for (int j = 0; j < 4; ++j) lv[row * 129 + c4 + j] = x.a[j];
  }
  __syncthreads();
  int l = t & 63, w = t >> 6;
  unsigned short* vt = vw + ((long)(bh * 32 + jt)) * 8192;   // [128][64]
  #pragma unroll
  for (int it = 0; it < 8; ++it) {
    int d = it * 16 + w * 4 + (l >> 4);
    int i = l & 15;                            // keys 4i..4i+3
    ushort4v o;
    #pragma unroll
    for (int j = 0; j < 4; ++j) o[j] = f2bf(lv[(4 * i + j) * 129 + d]);
    int off = d * 64 + ((((i >> 1) ^ (d & 7)) << 3) | ((i & 1) << 2));
    *(ushort4v*)(vt + off) = o;
  }
}

// ---------------- fused flash attention (causal), 4 waves x 16 q-rows
__global__ __launch_bounds__(256) void attn_fwd(const float* __restrict__ xq,
                                                const unsigned short* __restrict__ kw,
                                                const unsigned short* __restrict__ vw,
                                                float* __restrict__ out) {
  __shared__ __align__(16) unsigned short kL[64 * 128];   // [key][a], swizzled rows
  __shared__ __align__(16) unsigned short vL[128 * 64];   // [d][key], swizzled rows
  __shared__ __align__(16) unsigned short pL[4][16 * 64]; // per-wave [q][key], swizzled

  int bh = blockIdx.x;
  int qt = 31 - (int)blockIdx.y;               // big tiles dispatch first
  int b = bh >> 4, h = bh & (H_HEADS - 1);
  int t = threadIdx.x, l = t & 63, w = t >> 6;
  int lq = l & 15, g = l >> 4;
  int sq = qt * 64 + w * 16 + lq;              // this lane's q row (softmax owner)

  // ---- Q: load fp32, RoPE in-register, pack bf16 frags
  const float* qsrc = xq + ((long)(b * SLEN + sq)) * DMODEL + h * ADIM;
  float q32[4][8];
  #pragma unroll
  for (int c = 0; c < 4; ++c) {
    F4 lo, hi;
    lo.v = *(const float4*)(qsrc + c * 32 + g * 8);
    hi.v = *(const float4*)(qsrc + c * 32 + g * 8 + 4);
    #pragma unroll
    for (int j = 0; j < 4; ++j) { q32[c][j] = lo.a[j]; q32[c][j + 4] = hi.a[j]; }
  }
  short8 qf[4];
  #pragma unroll
  for (int c = 0; c < 2; ++c) {
    #pragma unroll
    for (int j = 0; j < 8; ++j) {
      int a = c * 32 + g * 8 + j;              // a < 64: pairs with a+64 (chunk c+2)
      float inv = exp2f(-(float)a * ROPE_C);
      float ang = (float)sq * inv;
      float sn, cs;
      sincosf(ang, &sn, &cs);
      qf[c    ][j] = (short)f2bf( q32[c][j] * cs + q32[c + 2][j] * sn);
      qf[c + 2][j] = (short)f2bf(-q32[c][j] * sn + q32[c + 2][j] * cs);
    }
  }

  float4v acc[8];
  #pragma unroll
  for (int i = 0; i < 8; ++i) acc[i] = (float4v){0.f, 0.f, 0.f, 0.f};
  float m_run = -1e30f, l_run = 0.f;
  const float sc = 0.08838834764831845f;       // 1/sqrt(128)

  const unsigned short* kbase_g = kw + (long)bh * SLEN * ADIM;
  const unsigned short* vbase_g = vw + (long)bh * 32 * 8192;
  int nt = qt + 1;

  for (int jt = 0; jt < nt; ++jt) {
    __syncthreads();                            // protect LDS reuse
    // ---- stage K (16KB) + V (16KB) via global_load_lds, linear copies
    const unsigned short* ks = kbase_g + (long)jt * 64 * ADIM;
    const unsigned short* vs = vbase_g + (long)jt * 8192;
    #pragma unroll
    for (int sg = 0; sg < 4; ++sg) {
      int seg = w * 4 + sg;                     // 512 elems = 1KB per wave-call
      __builtin_amdgcn_global_load_lds((gas_u32*)(ks + seg * 512 + l * 8),
                                       (las_u32*)&kL[seg * 512], 16, 0, 0);
      __builtin_amdgcn_global_load_lds((gas_u32*)(vs + seg * 512 + l * 8),
                                       (las_u32*)&vL[seg * 512], 16, 0, 0);
    }
    __syncthreads();

    // ---- swapped QK^T: S^T[key][q] = K · Q^T  (lane owns q-row lq)
    float4v accs[4];
    #pragma unroll
    for (int i = 0; i < 4; ++i) accs[i] = (float4v){0.f, 0.f, 0.f, 0.f};
    #pragma unroll
    for (int c = 0; c < 4; ++c) {
      int koff = (((c * 4 + g) ^ (lq & 7)) << 3);
      #pragma unroll
      for (int kb = 0; kb < 4; ++kb) {
        short8 kf = *(const short8*)&kL[(kb * 16 + lq) * 128 + koff];
        accs[kb] = __builtin_amdgcn_mfma_f32_16x16x32_bf16(kf, qf[c], accs[kb], 0, 0, 0);
      }
    }

    // ---- mask + online softmax (lane holds 16 scores of row lq)
    float p[16];
    bool diag = (jt == qt);
    #pragma unroll
    for (int kb = 0; kb < 4; ++kb) {
      #pragma unroll
      for (int r = 0; r < 4; ++r) {
        float x = accs[kb][r] * sc;
        if (diag) {
          int kidx = jt * 64 + kb * 16 + g * 4 + r;
          if (kidx > sq) x = -1e30f;
        }
        p[kb * 4 + r] = x;
      }
    }
    float tm = p[0];
    #pragma unroll
    for (int i = 1; i < 16; ++i) tm = fmaxf(tm, p[i]);
    tm = fmaxf(tm, __shfl_xor(tm, 16));
    tm = fmaxf(tm, __shfl_xor(tm, 32));
    float mnew = fmaxf(m_run, tm);
    float corr = __expf(m_run - mnew);
    float ts = 0.f;
    #pragma unroll
    for (int i = 0; i < 16; ++i) { p[i] = __expf(p[i] - mnew); ts += p[i]; }
    ts += __shfl_xor(ts, 16);
    ts += __shfl_xor(ts, 32);
    l_run = l_run * corr + ts;
    m_run = mnew;

    // ---- P -> bf16 -> per-wave LDS (swizzled)
    #pragma unroll
    for (int kb = 0; kb < 4; ++kb) {
      ushort4v pk;
      #pragma unroll
      for (int r = 0; r < 4; ++r) pk[r] = f2bf(p[kb * 4 + r]);
      int ch = (kb * 2 + (g >> 1)) ^ (lq & 7);
      *(ushort4v*)&pL[w][lq * 64 + (ch << 3) + ((g & 1) << 2)] = pk;
    }

    // ---- rescale O by exp(m_old - m_new), per out-row broadcast
    float cb[4];
    #pragma unroll
    for (int r = 0; r < 4; ++r) cb[r] = __shfl(corr, g * 4 + r);
    #pragma unroll
    for (int db = 0; db < 8; ++db) {
      #pragma unroll
      for (int r = 0; r < 4; ++r) acc[db][r] *= cb[r];
    }

    // ---- PV: O[q][d] += P · V
    #pragma unroll
    for (int kc = 0; kc < 2; ++kc) {
      int ch = ((kc * 4 + g) ^ (lq & 7)) << 3;
      short8 pa = *(const short8*)&pL[w][lq * 64 + ch];
      #pragma unroll
      for (int db = 0; db < 8; ++db) {
        int d = db * 16 + lq;                   // d&7 == lq&7
        short8 vb = *(const short8*)&vL[d * 64 + ch];
        acc[db] = __builtin_amdgcn_mfma_f32_16x16x32_bf16(pa, vb, acc[db], 0, 0, 0);
      }
    }
  }

  // ---- epilogue: normalize and store fp32
  float linv = 1.0f / l_run;
  float lb[4];
  #pragma unroll
  for (int r = 0; r < 4; ++r) lb[r] = __shfl(linv, g * 4 + r);
  #pragma unroll
  for (int db = 0; db < 8; ++db) {
    #pragma unroll
    for (int r = 0; r < 4; ++r) {
      int srow = qt * 64 + w * 16 + g * 4 + r;
      out[((long)(b * SLEN + srow)) * DMODEL + h * ADIM + db * 16 + lq] = acc[db][r] * lb[r];
    }
  }
}

extern "C" void kernel_launch(void* const* d_in, const int* in_sizes, int n_in,
                              void* d_out, int out_size, void* d_ws, size_t ws_size,
                              hipStream_t stream) {
  const float* xq = (const float*)d_in[0];
  const float* xk = (const float*)d_in[1];
  const float* xv = (const float*)d_in[2];
  float* outp = (float*)d_out;
  int B = in_sizes[0] / (SLEN * DMODEL);                    // 2
  size_t perT = (size_t)B * H_HEADS * SLEN * ADIM;          // bf16 elems per tensor
  unsigned short* kw = (unsigned short*)d_ws;               // 16.78 MB
  unsigned short* vw = kw + perT;                           // 16.78 MB  (total 33.6 MB ws)

  prep_k<<<dim3(B * 2048), 256, 0, stream>>>(xk, kw);
  prep_v<<<dim3(32, B * H_HEADS), 256, 0, stream>>>(xv, vw);
  attn_fwd<<<dim3(B * H_HEADS, 32), 256, 0, stream>>>(xq, kw, vw, outp);
}

// Round 2
// 97.201 us; speedup vs baseline: 1.0423x; 1.0423x over previous
//
#include <hip/hip_runtime.h>
#include <stdint.h>

#define H_HEADS 16
#define ADIM    128
#define SLEN    2048
#define DMODEL  2048

typedef __attribute__((ext_vector_type(8))) short  short8;   // bf16x8 MFMA frag
typedef __attribute__((ext_vector_type(4))) float  float4v;  // fp32x4 MFMA acc
typedef __attribute__((ext_vector_type(4))) unsigned short ushort4v;

typedef const __attribute__((address_space(1))) unsigned int gas_u32;
typedef __attribute__((address_space(3))) unsigned int las_u32;

union F4 { float4 v; float a[4]; };

__device__ __forceinline__ unsigned short f2bf(float f) {
  union { float f; unsigned u; } v; v.f = f;
  unsigned r = v.u + 0x7FFFu + ((v.u >> 16) & 1u);   // RNE
  return (unsigned short)(r >> 16);
}

__device__ __forceinline__ unsigned cvt_pk_bf16(float lo, float hi) {
  unsigned r;
  asm("v_cvt_pk_bf16_f32 %0, %1, %2" : "=v"(r) : "v"(lo), "v"(hi));
  return r;
}

// log2(10000)/64
#define ROPE_C 0.20762050593045935f
// (1/sqrt(128)) * log2(e)
#define C2LOG  0.12751879523103988f
// defer-max threshold: 8 nats in log2 units
#define THRZ   11.0f

// ---------------- prep_k: RoPE(K) -> bf16, [B*H][S][128], chunk ^= (s&7)
__global__ __launch_bounds__(256) void prep_k(const float* __restrict__ xk,
                                              unsigned short* __restrict__ kw) {
  int t = blockIdx.x * 256 + threadIdx.x;
  int i4 = t & 15;
  int h  = (t >> 4) & (H_HEADS - 1);
  int s  = (t >> 8) & (SLEN - 1);
  int b  = t >> 19;
  int i0 = i4 * 4;
  long ib = ((long)(b * SLEN + s)) * DMODEL + h * ADIM;
  F4 x1, x2;
  x1.v = *(const float4*)(xk + ib + i0);
  x2.v = *(const float4*)(xk + ib + i0 + 64);
  ushort4v o1, o2;
  #pragma unroll
  for (int j = 0; j < 4; ++j) {
    float inv = exp2f(-(float)(i0 + j) * ROPE_C);
    float ang = (float)s * inv;
    float sn, cs;
    sincosf(ang, &sn, &cs);
    o1[j] = f2bf( x1.a[j] * cs + x2.a[j] * sn);
    o2[j] = f2bf(-x1.a[j] * sn + x2.a[j] * cs);
  }
  long row = ((long)((b * H_HEADS + h) * SLEN + s)) * ADIM;
  int swz = s & 7;
  int c1 = ((((i0     ) >> 3) ^ swz) << 3) | (i0 & 7);
  int c2 = ((((i0 + 64) >> 3) ^ swz) << 3) | (i0 & 7);
  *(ushort4v*)(kw + row + c1) = o1;
  *(ushort4v*)(kw + row + c2) = o2;
}

// ---------------- prep_q: RoPE(Q) -> bf16, [B*H][S][128], linear
__global__ __launch_bounds__(256) void prep_q(const float* __restrict__ xq,
                                              unsigned short* __restrict__ qw) {
  int t = blockIdx.x * 256 + threadIdx.x;
  int i4 = t & 15;
  int h  = (t >> 4) & (H_HEADS - 1);
  int s  = (t >> 8) & (SLEN - 1);
  int b  = t >> 19;
  int i0 = i4 * 4;
  long ib = ((long)(b * SLEN + s)) * DMODEL + h * ADIM;
  F4 x1, x2;
  x1.v = *(const float4*)(xq + ib + i0);
  x2.v = *(const float4*)(xq + ib + i0 + 64);
  ushort4v o1, o2;
  #pragma unroll
  for (int j = 0; j < 4; ++j) {
    float inv = exp2f(-(float)(i0 + j) * ROPE_C);
    float ang = (float)s * inv;
    float sn, cs;
    sincosf(ang, &sn, &cs);
    o1[j] = f2bf( x1.a[j] * cs + x2.a[j] * sn);
    o2[j] = f2bf(-x1.a[j] * sn + x2.a[j] * cs);
  }
  long row = ((long)((b * H_HEADS + h) * SLEN + s)) * ADIM;
  *(ushort4v*)(qw + row + i0) = o1;
  *(ushort4v*)(qw + row + i0 + 64) = o2;
}

// ---------------- prep_v: transpose V per 64-key tile -> bf16 [B*H][tile][d][key], chunk ^= (d&7)
__global__ __launch_bounds__(256) void prep_v(const float* __restrict__ xv,
                                              unsigned short* __restrict__ vw) {
  __shared__ float lv[64 * 129];
  int jt = blockIdx.x;
  int bh = blockIdx.y;
  int b = bh >> 4, h = bh & (H_HEADS - 1);
  int t = threadIdx.x;
  #pragma unroll
  for (int it = 0; it < 8; ++it) {
    int id  = it * 256 + t;
    int row = id >> 5;
    int c4  = (id & 31) * 4;
    F4 x;
    x.v = *(const float4*)(xv + ((long)(b * SLEN + jt * 64 + row)) * DMODEL + h * ADIM + c4);
    #pragma unroll
    for (int j = 0; j < 4; ++j) lv[row * 129 + c4 + j] = x.a[j];
  }
  __syncthreads();
  int l = t & 63, w = t >> 6;
  unsigned short* vt = vw + ((long)(bh * 32 + jt)) * 8192;
  #pragma unroll
  for (int it = 0; it < 8; ++it) {
    int d = it * 16 + w * 4 + (l >> 4);
    int i = l & 15;
    ushort4v o;
    #pragma unroll
    for (int j = 0; j < 4; ++j) o[j] = f2bf(lv[(4 * i + j) * 129 + d]);
    int off = d * 64 + ((((i >> 1) ^ (d & 7)) << 3) | ((i & 1) << 2));
    *(ushort4v*)(vt + off) = o;
  }
}

// ---------------- fused causal flash attention, paired q-tiles, dbuf staging
__global__ __launch_bounds__(256) void attn_fwd(const unsigned short* __restrict__ qw,
                                                const unsigned short* __restrict__ kw,
                                                const unsigned short* __restrict__ vw,
                                                float* __restrict__ out) {
  __shared__ __align__(16) unsigned short kL[2][64 * 128];
  __shared__ __align__(16) unsigned short vL[2][128 * 64];
  __shared__ __align__(16) unsigned short pL[4][16 * 64];

  int bh = blockIdx.x;
  int pi = blockIdx.y;                 // 0..15
  int qtA = 31 - pi, qtB = pi;         // paired: work = 33 tiles per block
  int b = bh >> 4, h = bh & (H_HEADS - 1);
  int t = threadIdx.x, l = t & 63, w = t >> 6;
  int lq = l & 15, g = l >> 4;
  int lq7 = lq & 7;

  const unsigned short* qb      = qw + (long)bh * SLEN * ADIM;
  const unsigned short* kbase_g = kw + (long)bh * SLEN * ADIM;
  const unsigned short* vbase_g = vw + (long)bh * 32 * 8192;

  int sqA = qtA * 64 + w * 16 + lq;
  int sqB = qtB * 64 + w * 16 + lq;

  short8 qfA[4], qfB[4];
  #pragma unroll
  for (int c = 0; c < 4; ++c) {
    qfA[c] = *(const short8*)(qb + (long)sqA * ADIM + c * 32 + g * 8);
    qfB[c] = *(const short8*)(qb + (long)sqB * ADIM + c * 32 + g * 8);
  }

  float4v acc[8];
  #pragma unroll
  for (int i = 0; i < 8; ++i) acc[i] = (float4v){0.f, 0.f, 0.f, 0.f};
  float m_z = -1e30f, l_run = 0.f;     // log2-domain running max, per-lane partial sum

  auto STAGE = [&](int bufi, int jn) {
    const unsigned short* ks = kbase_g + (long)jn * (64 * ADIM);
    const unsigned short* vs = vbase_g + (long)jn * 8192;
    #pragma unroll
    for (int sg = 0; sg < 4; ++sg) {
      int seg = w * 4 + sg;
      __builtin_amdgcn_global_load_lds((gas_u32*)(ks + seg * 512 + l * 8),
                                       (las_u32*)&kL[bufi][seg * 512], 16, 0, 0);
      __builtin_amdgcn_global_load_lds((gas_u32*)(vs + seg * 512 + l * 8),
                                       (las_u32*)&vL[bufi][seg * 512], 16, 0, 0);
    }
  };

  auto COMPUTE = [&](int qt, int jt, int cur, int sq, const short8 (&qf)[4]) {
    // ---- swapped QK^T: S^T[key][q] = K · Q^T (lane owns q-row lq)
    float4v accs[4];
    #pragma unroll
    for (int i = 0; i < 4; ++i) accs[i] = (float4v){0.f, 0.f, 0.f, 0.f};
    const unsigned short* kl = &kL[cur][0];
    __builtin_amdgcn_s_setprio(1);
    #pragma unroll
    for (int c = 0; c < 4; ++c) {
      int koff = ((c * 4 + g) ^ lq7) << 3;
      #pragma unroll
      for (int kb = 0; kb < 4; ++kb) {
        short8 kf = *(const short8*)&kl[(kb * 16 + lq) * 128 + koff];
        accs[kb] = __builtin_amdgcn_mfma_f32_16x16x32_bf16(kf, qf[c], accs[kb], 0, 0, 0);
      }
    }
    __builtin_amdgcn_s_setprio(0);

    // ---- mask + log2-domain online softmax
    float s[16];
    #pragma unroll
    for (int kb = 0; kb < 4; ++kb)
      #pragma unroll
      for (int r = 0; r < 4; ++r) s[kb * 4 + r] = accs[kb][r];
    if (jt == qt) {
      #pragma unroll
      for (int kb = 0; kb < 4; ++kb)
        #pragma unroll
        for (int r = 0; r < 4; ++r)
          if (qt * 64 + kb * 16 + g * 4 + r > sq) s[kb * 4 + r] = -1e30f;
    }
    float t0 = fmaxf(fmaxf(s[0], s[1]),   fmaxf(s[2], s[3]));
    float t1 = fmaxf(fmaxf(s[4], s[5]),   fmaxf(s[6], s[7]));
    float t2 = fmaxf(fmaxf(s[8], s[9]),   fmaxf(s[10], s[11]));
    float t3 = fmaxf(fmaxf(s[12], s[13]), fmaxf(s[14], s[15]));
    float tm = fmaxf(fmaxf(t0, t1), fmaxf(t2, t3));
    tm = fmaxf(tm, __shfl_xor(tm, 16));
    tm = fmaxf(tm, __shfl_xor(tm, 32));
    float zt = tm * C2LOG;
    if (!__all(zt <= m_z + THRZ)) {     // defer-max: usually skipped after warm-up
      float mn = fmaxf(m_z, zt);
      float corr = exp2f(m_z - mn);
      m_z = mn;
      l_run *= corr;
      float cb[4];
      #pragma unroll
      for (int r = 0; r < 4; ++r) cb[r] = __shfl(corr, g * 4 + r);
      #pragma unroll
      for (int db = 0; db < 8; ++db)
        #pragma unroll
        for (int r = 0; r < 4; ++r) acc[db][r] *= cb[r];
    }
    float p[16];
    float ts = 0.f;
    #pragma unroll
    for (int i = 0; i < 16; ++i) { p[i] = exp2f(fmaf(s[i], C2LOG, -m_z)); ts += p[i]; }
    l_run += ts;

    // ---- P -> bf16 (packed cvt) -> per-wave LDS (swizzled)
    #pragma unroll
    for (int kb = 0; kb < 4; ++kb) {
      uint2 u;
      u.x = cvt_pk_bf16(p[kb * 4 + 0], p[kb * 4 + 1]);
      u.y = cvt_pk_bf16(p[kb * 4 + 2], p[kb * 4 + 3]);
      int ch = (kb * 2 + (g >> 1)) ^ lq7;
      *(uint2*)&pL[w][lq * 64 + (ch << 3) + ((g & 1) << 2)] = u;
    }

    // ---- PV: O[q][d] += P · V
    const unsigned short* vl = &vL[cur][0];
    __builtin_amdgcn_s_setprio(1);
    #pragma unroll
    for (int kc = 0; kc < 2; ++kc) {
      int ch = ((kc * 4 + g) ^ lq7) << 3;
      short8 pa = *(const short8*)&pL[w][lq * 64 + ch];
      #pragma unroll
      for (int db = 0; db < 8; ++db) {
        short8 vb = *(const short8*)&vl[(db * 16 + lq) * 64 + ch];
        acc[db] = __builtin_amdgcn_mfma_f32_16x16x32_bf16(pa, vb, acc[db], 0, 0, 0);
      }
    }
    __builtin_amdgcn_s_setprio(0);
  };

  auto EPI = [&](int qt) {
    float lt = l_run + __shfl_xor(l_run, 16);
    lt += __shfl_xor(lt, 32);
    float linv = 1.0f / lt;
    float lb[4];
    #pragma unroll
    for (int r = 0; r < 4; ++r) lb[r] = __shfl(linv, g * 4 + r);
    #pragma unroll
    for (int db = 0; db < 8; ++db)
      #pragma unroll
      for (int r = 0; r < 4; ++r)
        out[((long)(b * SLEN + qt * 64 + w * 16 + g * 4 + r)) * DMODEL + h * ADIM + db * 16 + lq]
          = acc[db][r] * lb[r];
  };

  // ---- prologue: stage tile 0
  STAGE(0, 0);
  asm volatile("s_waitcnt vmcnt(0)" ::: "memory");
  __builtin_amdgcn_s_barrier();
  int cur = 0;

  // ---- q-tile A (the big one); last iteration prefetches qtB's tile 0
  for (int jt = 0; jt <= qtA; ++jt) {
    int jn = (jt < qtA) ? jt + 1 : 0;
    STAGE(cur ^ 1, jn);
    COMPUTE(qtA, jt, cur, sqA, qfA);
    asm volatile("s_waitcnt vmcnt(0)" ::: "memory");
    __builtin_amdgcn_s_barrier();
    cur ^= 1;
  }
  EPI(qtA);
  #pragma unroll
  for (int i = 0; i < 8; ++i) acc[i] = (float4v){0.f, 0.f, 0.f, 0.f};
  m_z = -1e30f; l_run = 0.f;

  // ---- q-tile B
  for (int jt = 0; jt <= qtB; ++jt) {
    if (jt < qtB) STAGE(cur ^ 1, jt + 1);
    COMPUTE(qtB, jt, cur, sqB, qfB);
    asm volatile("s_waitcnt vmcnt(0)" ::: "memory");
    __builtin_amdgcn_s_barrier();
    cur ^= 1;
  }
  EPI(qtB);
}

extern "C" void kernel_launch(void* const* d_in, const int* in_sizes, int n_in,
                              void* d_out, int out_size, void* d_ws, size_t ws_size,
                              hipStream_t stream) {
  const float* xq = (const float*)d_in[0];
  const float* xk = (const float*)d_in[1];
  const float* xv = (const float*)d_in[2];
  float* outp = (float*)d_out;
  int B = in_sizes[0] / (SLEN * DMODEL);                    // 2
  size_t perT = (size_t)B * H_HEADS * SLEN * ADIM;          // bf16 elems per tensor
  unsigned short* kw  = (unsigned short*)d_ws;              // 16.78 MB
  unsigned short* vw  = kw + perT;                          // 16.78 MB
  unsigned short* qw2 = vw + perT;                          // 16.78 MB (total ~50.3 MB ws)

  prep_k<<<dim3(B * 2048), 256, 0, stream>>>(xk, kw);
  prep_v<<<dim3(32, B * H_HEADS), 256, 0, stream>>>(xv, vw);
  prep_q<<<dim3(B * 2048), 256, 0, stream>>>(xq, qw2);
  attn_fwd<<<dim3(B * H_HEADS, 16), 256, 0, stream>>>(qw2, kw, vw, outp);
}

// Round 3
// 88.125 us; speedup vs baseline: 1.1497x; 1.1030x over previous
//
#include <hip/hip_runtime.h>
#include <stdint.h>

#define H_HEADS 16
#define ADIM    128
#define SLEN    2048
#define DMODEL  2048

typedef __attribute__((ext_vector_type(8))) short  short8;   // bf16x8 MFMA frag
typedef __attribute__((ext_vector_type(4))) float  float4v;  // fp32x4 MFMA acc
typedef __attribute__((ext_vector_type(4))) unsigned short ushort4v;

typedef const __attribute__((address_space(1))) unsigned int gas_u32;
typedef __attribute__((address_space(3))) unsigned int las_u32;

union F4 { float4 v; float a[4]; };
union PU { unsigned u[4]; short8 s; };

struct CTrue  { static constexpr bool value = true;  };
struct CFalse { static constexpr bool value = false; };

__device__ __forceinline__ unsigned short f2bf(float f) {
  union { float f; unsigned u; } v; v.f = f;
  unsigned r = v.u + 0x7FFFu + ((v.u >> 16) & 1u);   // RNE
  return (unsigned short)(r >> 16);
}

__device__ __forceinline__ unsigned cvt_pk_bf16(float lo, float hi) {
  unsigned r;
  asm("v_cvt_pk_bf16_f32 %0, %1, %2" : "=v"(r) : "v"(lo), "v"(hi));
  return r;
}

// rows: a' = [a0,b0,a2,b2]-style double swap: after p32+p16,
// a = [x@r0, x@r2, y@r0, y@r2], b = [x@r1, x@r3, y@r1, y@r3]  (x=a_in, y=b_in)
__device__ __forceinline__ void xswap(unsigned& a, unsigned& b) {
  asm volatile("v_permlane32_swap_b32 %0, %1" : "+v"(a), "+v"(b));
  asm volatile("v_permlane16_swap_b32 %0, %1" : "+v"(a), "+v"(b));
}

// log2(10000)/64
#define ROPE_C 0.20762050593045935f
// (1/sqrt(128)) * log2(e)
#define C2LOG  0.12751879523103988f
// defer-max threshold (log2 units ~ 8 nats)
#define THRZ   11.0f

// ---------------- prep_k: RoPE(K) -> bf16, [B*H][S][128], chunk ^= (s&7)
__global__ __launch_bounds__(256) void prep_k(const float* __restrict__ xk,
                                              unsigned short* __restrict__ kw) {
  int t = blockIdx.x * 256 + threadIdx.x;
  int i4 = t & 15;
  int h  = (t >> 4) & (H_HEADS - 1);
  int s  = (t >> 8) & (SLEN - 1);
  int b  = t >> 19;
  int i0 = i4 * 4;
  long ib = ((long)(b * SLEN + s)) * DMODEL + h * ADIM;
  F4 x1, x2;
  x1.v = *(const float4*)(xk + ib + i0);
  x2.v = *(const float4*)(xk + ib + i0 + 64);
  ushort4v o1, o2;
  #pragma unroll
  for (int j = 0; j < 4; ++j) {
    float inv = exp2f(-(float)(i0 + j) * ROPE_C);
    float ang = (float)s * inv;
    float sn, cs;
    sincosf(ang, &sn, &cs);
    o1[j] = f2bf( x1.a[j] * cs + x2.a[j] * sn);
    o2[j] = f2bf(-x1.a[j] * sn + x2.a[j] * cs);
  }
  long row = ((long)((b * H_HEADS + h) * SLEN + s)) * ADIM;
  int swz = s & 7;
  int c1 = ((((i0     ) >> 3) ^ swz) << 3) | (i0 & 7);
  int c2 = ((((i0 + 64) >> 3) ^ swz) << 3) | (i0 & 7);
  *(ushort4v*)(kw + row + c1) = o1;
  *(ushort4v*)(kw + row + c2) = o2;
}

// ---------------- prep_v: transpose V per 64-key tile -> bf16 [B*H][tile][d][key], chunk ^= (d&7)
__global__ __launch_bounds__(256) void prep_v(const float* __restrict__ xv,
                                              unsigned short* __restrict__ vw) {
  __shared__ float lv[64 * 129];
  int jt = blockIdx.x;
  int bh = blockIdx.y;
  int b = bh >> 4, h = bh & (H_HEADS - 1);
  int t = threadIdx.x;
  #pragma unroll
  for (int it = 0; it < 8; ++it) {
    int id  = it * 256 + t;
    int row = id >> 5;
    int c4  = (id & 31) * 4;
    F4 x;
    x.v = *(const float4*)(xv + ((long)(b * SLEN + jt * 64 + row)) * DMODEL + h * ADIM + c4);
    #pragma unroll
    for (int j = 0; j < 4; ++j) lv[row * 129 + c4 + j] = x.a[j];
  }
  __syncthreads();
  int l = t & 63, w = t >> 6;
  unsigned short* vt = vw + ((long)(bh * 32 + jt)) * 8192;
  #pragma unroll
  for (int it = 0; it < 8; ++it) {
    int d = it * 16 + w * 4 + (l >> 4);
    int i = l & 15;
    ushort4v o;
    #pragma unroll
    for (int j = 0; j < 4; ++j) o[j] = f2bf(lv[(4 * i + j) * 129 + d]);
    int off = d * 64 + ((((i >> 1) ^ (d & 7)) << 3) | ((i & 1) << 2));
    *(ushort4v*)(vt + off) = o;
  }
}

// ---------------- fused causal flash attention, fused-pair k-sweep
__global__ __launch_bounds__(256, 2) void attn_fwd(const float* __restrict__ xq,
                                                   const unsigned short* __restrict__ kw,
                                                   const unsigned short* __restrict__ vw,
                                                   float* __restrict__ out) {
  __shared__ __align__(16) unsigned short kL[2][64 * 128];
  __shared__ __align__(16) unsigned short vL[2][128 * 64];

  int bh = blockIdx.x;
  int pi = blockIdx.y;                  // 0..15
  int qtA = 31 - pi, qtB = pi;          // qtA >= 16 > qtB; A sweep covers B's range
  int b = bh >> 4, h = bh & (H_HEADS - 1);
  int t = threadIdx.x, l = t & 63, w = t >> 6;
  int lq = l & 15, g = l >> 4, lq7 = lq & 7;

  int sqA = qtA * 64 + w * 16 + lq;
  int sqB = qtB * 64 + w * 16 + lq;

  // ---- Q: load fp32, RoPE in-register, pack bf16 frags (both groups)
  short8 qfA[4], qfB[4];
  auto ROPEQ = [&](int sq, short8 (&qf)[4]) {
    const float* qsrc = xq + ((long)(b * SLEN + sq)) * DMODEL + h * ADIM;
    float q32[4][8];
    #pragma unroll
    for (int c = 0; c < 4; ++c) {
      F4 lo, hi;
      lo.v = *(const float4*)(qsrc + c * 32 + g * 8);
      hi.v = *(const float4*)(qsrc + c * 32 + g * 8 + 4);
      #pragma unroll
      for (int j = 0; j < 4; ++j) { q32[c][j] = lo.a[j]; q32[c][j + 4] = hi.a[j]; }
    }
    #pragma unroll
    for (int c = 0; c < 2; ++c) {
      #pragma unroll
      for (int j = 0; j < 8; ++j) {
        int a = c * 32 + g * 8 + j;
        float inv = exp2f(-(float)a * ROPE_C);
        float ang = (float)sq * inv;
        float sn, cs;
        sincosf(ang, &sn, &cs);
        qf[c    ][j] = (short)f2bf( q32[c][j] * cs + q32[c + 2][j] * sn);
        qf[c + 2][j] = (short)f2bf(-q32[c][j] * sn + q32[c + 2][j] * cs);
      }
    }
  };
  ROPEQ(sqA, qfA);
  ROPEQ(sqB, qfB);

  float4v accA[8], accB[8];
  #pragma unroll
  for (int i = 0; i < 8; ++i) { accA[i] = (float4v){0.f,0.f,0.f,0.f}; accB[i] = (float4v){0.f,0.f,0.f,0.f}; }
  float mA = -1e30f, lA = 0.f, mB = -1e30f, lB = 0.f;

  const unsigned short* kbase_g = kw + (long)bh * SLEN * ADIM;
  const unsigned short* vbase_g = vw + (long)bh * 32 * 8192;

  auto STAGE = [&](int bufi, int jn) {
    const unsigned short* ks = kbase_g + (long)jn * (64 * ADIM);
    const unsigned short* vs = vbase_g + (long)jn * 8192;
    #pragma unroll
    for (int sg = 0; sg < 4; ++sg) {
      int seg = w * 4 + sg;
      __builtin_amdgcn_global_load_lds((gas_u32*)(ks + seg * 512 + l * 8),
                                       (las_u32*)&kL[bufi][seg * 512], 16, 0, 0);
      __builtin_amdgcn_global_load_lds((gas_u32*)(vs + seg * 512 + l * 8),
                                       (las_u32*)&vL[bufi][seg * 512], 16, 0, 0);
    }
  };

  // ---- softmax (log2-domain, defer-max) + in-register P->A-frag permute
  auto SOFTMAX = [&](float4v (&sv)[4], float& m_z, float& l_run, float4v (&acc)[8],
                     int sq, int qt, int jt, short8 (&pa)[2]) {
    float s[16];
    #pragma unroll
    for (int kb = 0; kb < 4; ++kb)
      #pragma unroll
      for (int r = 0; r < 4; ++r) s[kb * 4 + r] = sv[kb][r];
    if (jt == qt) {
      #pragma unroll
      for (int kb = 0; kb < 4; ++kb)
        #pragma unroll
        for (int r = 0; r < 4; ++r)
          if (qt * 64 + kb * 16 + g * 4 + r > sq) s[kb * 4 + r] = -1e30f;
    }
    float t0 = fmaxf(fmaxf(s[0], s[1]),   fmaxf(s[2], s[3]));
    float t1 = fmaxf(fmaxf(s[4], s[5]),   fmaxf(s[6], s[7]));
    float t2 = fmaxf(fmaxf(s[8], s[9]),   fmaxf(s[10], s[11]));
    float t3 = fmaxf(fmaxf(s[12], s[13]), fmaxf(s[14], s[15]));
    float tm = fmaxf(fmaxf(t0, t1), fmaxf(t2, t3));
    tm = fmaxf(tm, __shfl_xor(tm, 16));
    tm = fmaxf(tm, __shfl_xor(tm, 32));
    float zt = tm * C2LOG;
    if (!__all(zt <= m_z + THRZ)) {
      float mn = fmaxf(m_z, zt);
      float corr = exp2f(m_z - mn);
      m_z = mn;
      l_run *= corr;
      float cb[4];
      #pragma unroll
      for (int r = 0; r < 4; ++r) cb[r] = __shfl(corr, g * 4 + r);
      #pragma unroll
      for (int db = 0; db < 8; ++db)
        #pragma unroll
        for (int r = 0; r < 4; ++r) acc[db][r] *= cb[r];
    }
    float p[16];
    float ts = 0.f;
    #pragma unroll
    for (int i = 0; i < 16; ++i) { p[i] = exp2f(fmaf(s[i], C2LOG, -m_z)); ts += p[i]; }
    l_run += ts;

    // pack to bf16 pairs: L[kb] = (r0,r1), H[kb] = (r2,r3)
    unsigned L[4], Hh[4];
    #pragma unroll
    for (int kb = 0; kb < 4; ++kb) {
      L[kb]  = cvt_pk_bf16(p[kb * 4 + 0], p[kb * 4 + 1]);
      Hh[kb] = cvt_pk_bf16(p[kb * 4 + 2], p[kb * 4 + 3]);
    }
    // redistribute: dest lane (lq,g) A-frag kc needs keys kc*32+g*8+j
    // held by lanes g'=2(g&1)(+1), regs of kb=2kc+(g>>1)
    xswap(L[0], L[1]);  xswap(Hh[0], Hh[1]);   // -> kc=0 words {0,2},{1,3}
    xswap(L[2], L[3]);  xswap(Hh[2], Hh[3]);   // -> kc=1
    PU a0, a1;
    a0.u[0] = L[0]; a0.u[1] = Hh[0]; a0.u[2] = L[1]; a0.u[3] = Hh[1];
    a1.u[0] = L[2]; a1.u[1] = Hh[2]; a1.u[2] = L[3]; a1.u[3] = Hh[3];
    pa[0] = a0.s; pa[1] = a1.s;
  };

  auto QK = [&](auto BOTH, int cur, float4v (&sA)[4], float4v (&sB)[4]) {
    const unsigned short* kl = &kL[cur][0];
    __builtin_amdgcn_s_setprio(1);
    #pragma unroll
    for (int c = 0; c < 4; ++c) {
      int koff = ((c * 4 + g) ^ lq7) << 3;
      #pragma unroll
      for (int kb = 0; kb < 4; ++kb) {
        short8 kf = *(const short8*)&kl[(kb * 16 + lq) * 128 + koff];
        sA[kb] = __builtin_amdgcn_mfma_f32_16x16x32_bf16(kf, qfA[c], sA[kb], 0, 0, 0);
        if constexpr (decltype(BOTH)::value)
          sB[kb] = __builtin_amdgcn_mfma_f32_16x16x32_bf16(kf, qfB[c], sB[kb], 0, 0, 0);
      }
    }
    __builtin_amdgcn_s_setprio(0);
  };

  auto PV = [&](auto BOTH, int cur, short8 (&paA)[2], short8 (&paB)[2]) {
    const unsigned short* vl = &vL[cur][0];
    __builtin_amdgcn_s_setprio(1);
    #pragma unroll
    for (int kc = 0; kc < 2; ++kc) {
      int ch = ((kc * 4 + g) ^ lq7) << 3;
      #pragma unroll
      for (int db = 0; db < 8; ++db) {
        short8 vb = *(const short8*)&vl[(db * 16 + lq) * 64 + ch];
        accA[db] = __builtin_amdgcn_mfma_f32_16x16x32_bf16(paA[kc], vb, accA[db], 0, 0, 0);
        if constexpr (decltype(BOTH)::value)
          accB[db] = __builtin_amdgcn_mfma_f32_16x16x32_bf16(paB[kc], vb, accB[db], 0, 0, 0);
      }
    }
    __builtin_amdgcn_s_setprio(0);
  };

  // ---- prologue
  STAGE(0, 0);
  asm volatile("s_waitcnt vmcnt(0)" ::: "memory");
  __builtin_amdgcn_s_barrier();
  int cur = 0;

  // ---- single fused k-sweep: A always, B while jt <= qtB (shared kf/vb reads)
  for (int jt = 0; jt <= qtA; ++jt) {
    if (jt < qtA) STAGE(cur ^ 1, jt + 1);
    bool doB = (jt <= qtB);
    float4v sA[4], sB[4];
    #pragma unroll
    for (int i = 0; i < 4; ++i) { sA[i] = (float4v){0.f,0.f,0.f,0.f}; sB[i] = (float4v){0.f,0.f,0.f,0.f}; }
    short8 paA[2], paB[2];
    if (doB) QK(CTrue{},  cur, sA, sB);
    else     QK(CFalse{}, cur, sA, sB);
    SOFTMAX(sA, mA, lA, accA, sqA, qtA, jt, paA);
    if (doB) SOFTMAX(sB, mB, lB, accB, sqB, qtB, jt, paB);
    if (doB) PV(CTrue{},  cur, paA, paB);
    else     PV(CFalse{}, cur, paA, paB);
    asm volatile("s_waitcnt vmcnt(0)" ::: "memory");
    __builtin_amdgcn_s_barrier();
    cur ^= 1;
  }

  // ---- epilogue: normalize and store fp32 (both groups)
  auto EPI = [&](int qt, float l_run, float4v (&acc)[8]) {
    float lt = l_run + __shfl_xor(l_run, 16);
    lt += __shfl_xor(lt, 32);
    float linv = 1.0f / lt;
    float lb[4];
    #pragma unroll
    for (int r = 0; r < 4; ++r) lb[r] = __shfl(linv, g * 4 + r);
    #pragma unroll
    for (int db = 0; db < 8; ++db)
      #pragma unroll
      for (int r = 0; r < 4; ++r)
        out[((long)(b * SLEN + qt * 64 + w * 16 + g * 4 + r)) * DMODEL + h * ADIM + db * 16 + lq]
          = acc[db][r] * lb[r];
  };
  EPI(qtA, lA, accA);
  EPI(qtB, lB, accB);
}

extern "C" void kernel_launch(void* const* d_in, const int* in_sizes, int n_in,
                              void* d_out, int out_size, void* d_ws, size_t ws_size,
                              hipStream_t stream) {
  const float* xq = (const float*)d_in[0];
  const float* xk = (const float*)d_in[1];
  const float* xv = (const float*)d_in[2];
  float* outp = (float*)d_out;
  int B = in_sizes[0] / (SLEN * DMODEL);                    // 2
  size_t perT = (size_t)B * H_HEADS * SLEN * ADIM;          // bf16 elems per tensor
  unsigned short* kw = (unsigned short*)d_ws;               // 16.78 MB
  unsigned short* vw = kw + perT;                           // 16.78 MB (total ~33.6 MB ws)

  prep_k<<<dim3(B * 2048), 256, 0, stream>>>(xk, kw);
  prep_v<<<dim3(32, B * H_HEADS), 256, 0, stream>>>(xv, vw);
  attn_fwd<<<dim3(B * H_HEADS, 16), 256, 0, stream>>>(xq, kw, vw, outp);
}